// Round 1
// baseline (1010.805 us; speedup 1.0000x reference)
//
#include <hip/hip_runtime.h>
#include <math.h>

#define D_MODEL 1024
#define MEM_HEADS 4
#define KNN 32
#define KEY_DIM 288
#define VALUE_DIM 512
#define Q_RANK 512
#define NUM_BUCKETS 18
#define BUCKET_DIM 16
#define NTOK 2048                      // BATCH * SEQ
#define ROWS (NTOK * MEM_HEADS)        // 8192
#define QDIM (MEM_HEADS * KEY_DIM)     // 1152

typedef unsigned short u16;
typedef __attribute__((ext_vector_type(8))) short bfrag;   // 8 bf16 halves (4 VGPRs)
typedef __attribute__((ext_vector_type(4))) float f32x4;   // MFMA C/D frag
typedef __attribute__((ext_vector_type(4))) unsigned short u16x4;

__device__ __forceinline__ u16 f2bf(float x) {  // RNE fp32->bf16
    unsigned int u = __builtin_bit_cast(unsigned int, x);
    u += 0x7FFFu + ((u >> 16) & 1u);
    return (u16)(u >> 16);
}
__device__ __forceinline__ float bf2f(u16 h) {
    unsigned int u = ((unsigned int)h) << 16;
    return __builtin_bit_cast(float, u);
}

// ---------------------------------------------------------------------------
// split_prep: materialize bf16 split planes ONCE per call.
// Previously every GEMM block recomputed the 3-stage split of its tiles
// (~400 VALU instr/lane/K-chunk; x split 8x, qd_w 32x, qu_w 32x, vp_w 32x).
// Splits here are bit-identical to the old in-block splits (same f2bf chain
// on the same fp32 values), so downstream MFMA operands are unchanged.
// ---------------------------------------------------------------------------
__global__ __launch_bounds__(256) void split_prep(
    const float* __restrict__ x, const float* __restrict__ qdw,
    const float* __restrict__ quw, const float* __restrict__ vpw,
    u16* __restrict__ xs, u16* __restrict__ qds,
    u16* __restrict__ qus, u16* __restrict__ vps)
{
    const float* src; u16* dst; int n; int ns;
    switch (blockIdx.y) {
        case 0:  src = x;   dst = xs;  n = NTOK * D_MODEL;     ns = 3; break;
        case 1:  src = qdw; dst = qds; n = Q_RANK * D_MODEL;   ns = 3; break;
        case 2:  src = quw; dst = qus; n = QDIM * Q_RANK;      ns = 3; break;
        default: src = vpw; dst = vps; n = D_MODEL * VALUE_DIM; ns = 2; break;
    }
    const int n4 = n >> 2;
    for (int i = blockIdx.x * 256 + threadIdx.x; i < n4; i += gridDim.x * 256) {
        const float4 v = ((const float4*)src)[i];
        float c0 = v.x, c1 = v.y, c2 = v.z, c3 = v.w;
        for (int s = 0; s < ns; ++s) {           // ns is block-uniform
            const u16 h0 = f2bf(c0), h1 = f2bf(c1), h2 = f2bf(c2), h3 = f2bf(c3);
            const u16x4 h = {h0, h1, h2, h3};
            *(u16x4*)(dst + (size_t)s * n + (size_t)i * 4) = h;
            c0 -= bf2f(h0); c1 -= bf2f(h1); c2 -= bf2f(h2); c3 -= bf2f(h3);
        }
    }
}

// ---------------------------------------------------------------------------
// Pre-split MFMA GEMM: C[M,N] = sum_products A_s[M,K] @ B_s[N,K]^T (+bias).
// Inputs are bf16 planes (s-major, plane stride M*K / N*K). MODE=3 keeps the
// bf16x6 product set {00,01,10,11,02,20} (fp32-equiv, REQUIRED for q path:
// trellis compares penalties at ~1e-5); MODE=2 keeps bf16x3 {00,01,10}.
// OUTS=0: fp32 output. OUTS>0: write OUTS bf16 split planes (plane stride
// M*N) -- used by GEMM1 so q_mid feeds GEMM2 without a separate split pass.
// 64x64 tile, BK=32, 256 threads; 4 waves 2x2, each wave 2x2 16x16x32 tiles.
// 64-tile so GEMM1's grid is 256 blocks (grid fill). LDS row stride 40
// halves (conflict-free frag reads). Frag layouts per m89/m91.
// ---------------------------------------------------------------------------
#define LSTR 40
template<int MODE, int OUTS>
__global__ __launch_bounds__(256) void gemm_nt_pre(
    const u16* __restrict__ A, const u16* __restrict__ B,
    const float* __restrict__ bias, float* __restrict__ Cf,
    u16* __restrict__ Cs, int M, int N, int K)
{
    __shared__ __align__(16) u16 As[MODE][64][LSTR];
    __shared__ __align__(16) u16 Bs[MODE][64][LSTR];

    const int tid  = threadIdx.x;
    const int bm   = blockIdx.y * 64;
    const int bn   = blockIdx.x * 64;
    const int wave = tid >> 6;
    const int lane = tid & 63;
    const int wr   = wave & 1;          // wave m-half (32 rows)
    const int wc   = wave >> 1;         // wave n-half (32 cols)
    const int l15  = lane & 15;
    const int quad = lane >> 4;

    const int sr = tid >> 2;            // staging row 0..63
    const int sg = tid & 3;             // staging 8-half segment

    f32x4 acc[2][2];
#pragma unroll
    for (int i = 0; i < 2; ++i)
#pragma unroll
        for (int j = 0; j < 2; ++j) acc[i][j] = (f32x4){0.f, 0.f, 0.f, 0.f};

    const size_t pA = (size_t)M * K;
    const size_t pB = (size_t)N * K;
    const u16* Ap = A + (size_t)(bm + sr) * K + sg * 8;
    const u16* Bp = B + (size_t)(bn + sr) * K + sg * 8;

    for (int k0 = 0; k0 < K; k0 += 32) {
        bfrag la[MODE], lb[MODE];
#pragma unroll
        for (int s = 0; s < MODE; ++s) {
            la[s] = *(const bfrag*)(Ap + s * pA + k0);
            lb[s] = *(const bfrag*)(Bp + s * pB + k0);
        }

        __syncthreads();   // prior chunk's frag reads done
#pragma unroll
        for (int s = 0; s < MODE; ++s) {
            *(bfrag*)&As[s][sr][sg * 8] = la[s];
            *(bfrag*)&Bs[s][sr][sg * 8] = lb[s];
        }
        __syncthreads();   // tiles visible

        bfrag af[MODE][2], bf[MODE][2];
#pragma unroll
        for (int t = 0; t < 2; ++t) {
            const int mr = wr * 32 + t * 16 + l15;
            const int nr = wc * 32 + t * 16 + l15;
#pragma unroll
            for (int s = 0; s < MODE; ++s) {
                af[s][t] = *(const bfrag*)&As[s][mr][quad * 8];
                bf[s][t] = *(const bfrag*)&Bs[s][nr][quad * 8];
            }
        }
#pragma unroll
        for (int mt = 0; mt < 2; ++mt)
#pragma unroll
            for (int nt = 0; nt < 2; ++nt) {
                f32x4 c = acc[mt][nt];
                c = __builtin_amdgcn_mfma_f32_16x16x32_bf16(af[0][mt], bf[0][nt], c, 0, 0, 0);
                c = __builtin_amdgcn_mfma_f32_16x16x32_bf16(af[0][mt], bf[1][nt], c, 0, 0, 0);
                c = __builtin_amdgcn_mfma_f32_16x16x32_bf16(af[1][mt], bf[0][nt], c, 0, 0, 0);
                if (MODE == 3) {
                    c = __builtin_amdgcn_mfma_f32_16x16x32_bf16(af[1][mt], bf[1][nt], c, 0, 0, 0);
                    c = __builtin_amdgcn_mfma_f32_16x16x32_bf16(af[0][mt], bf[2][nt], c, 0, 0, 0);
                    c = __builtin_amdgcn_mfma_f32_16x16x32_bf16(af[2][mt], bf[0][nt], c, 0, 0, 0);
                }
                acc[mt][nt] = c;
            }
    }

    // epilogue: C/D frag (col=l15, row=quad*4+g) -> row-major out (+bias)
#pragma unroll
    for (int nt = 0; nt < 2; ++nt) {
        const int col = bn + wc * 32 + nt * 16 + l15;
        const float bv = bias ? bias[col] : 0.f;
#pragma unroll
        for (int mt = 0; mt < 2; ++mt) {
            const int rowb = bm + wr * 32 + mt * 16 + quad * 4;
#pragma unroll
            for (int g = 0; g < 4; ++g) {
                float c = acc[mt][nt][g] + bv;
                const size_t off = (size_t)(rowb + g) * N + col;
                if (OUTS == 0) {
                    Cf[off] = c;
                } else {
#pragma unroll
                    for (int s = 0; s < OUTS; ++s) {
                        const u16 h = f2bf(c);
                        Cs[(size_t)s * ((size_t)M * N) + off] = h;
                        c -= bf2f(h);
                    }
                }
            }
        }
    }
}

// ---------------------------------------------------------------------------
// Trellis beam search — logic IDENTICAL to the passing kernel (arithmetic
// order unchanged; dlt in registers, float4 q loads). Stable two-pointer
// merge == jax.lax.top_k tie-break (A-side on ties). Softmax: penalty 0
// always survives => softmax(best - pen) == exp(-pen)/Z.
// ---------------------------------------------------------------------------
__global__ __launch_bounds__(64) void trellis_kernel(
    const float* __restrict__ q, const float* __restrict__ keys,
    float* __restrict__ sc_out, int* __restrict__ idx_out)
{
    __shared__ float s_keys[MEM_HEADS * NUM_BUCKETS * 2 * BUCKET_DIM]; // 2304
    __shared__ float penB[2][KNN][64];
    __shared__ int   mskB[2][KNN][64];

    const int tid = threadIdx.x;
    for (int i = tid; i < MEM_HEADS * NUM_BUCKETS * 2 * BUCKET_DIM; i += 64)
        s_keys[i] = keys[i];
    __syncthreads();

    const int r = blockIdx.x * 64 + tid;
    const int h = r & 3;
    const float* qr = q + (size_t)r * KEY_DIM;

    float dlt[NUM_BUCKETS];
    int code = 0;
#pragma unroll
    for (int m = 0; m < NUM_BUCKETS; ++m) {
        const float* km = s_keys + h * (NUM_BUCKETS * 32) + m * 32;
        const float4 q0 = *(const float4*)(qr + m * BUCKET_DIM);
        const float4 q1 = *(const float4*)(qr + m * BUCKET_DIM + 4);
        const float4 q2 = *(const float4*)(qr + m * BUCKET_DIM + 8);
        const float4 q3 = *(const float4*)(qr + m * BUCKET_DIM + 12);
        const float qv[16] = {q0.x,q0.y,q0.z,q0.w, q1.x,q1.y,q1.z,q1.w,
                              q2.x,q2.y,q2.z,q2.w, q3.x,q3.y,q3.z,q3.w};
        float s0 = 0.f, s1 = 0.f;
#pragma unroll
        for (int d = 0; d < BUCKET_DIM; ++d) {
            s0 += qv[d] * km[d];
            s1 += qv[d] * km[16 + d];
        }
        dlt[m] = fabsf(s0 - s1);
        if (s1 > s0) code |= (1 << m);
    }

    penB[0][0][tid] = 0.f;
    mskB[0][0][tid] = 0;
    int nb = 1, cur = 0;
#pragma unroll
    for (int t = 0; t < NUM_BUCKETS; ++t) {
        const float d = dlt[t];
        const int nk = min(KNN, nb * 2);
        const int nxt = cur ^ 1;
        int i = 0, j = 0;
        for (int o = 0; o < nk; ++o) {
            const float pa = (i < nb) ? penB[cur][i][tid] : 3.4e38f;
            const float pb = (j < nb) ? (penB[cur][j][tid] + d) : 3.4e38f;
            if (pa <= pb) {              // tie -> A side, matches top_k
                penB[nxt][o][tid] = pa;
                mskB[nxt][o][tid] = mskB[cur][i][tid];
                ++i;
            } else {
                penB[nxt][o][tid] = pb;
                mskB[nxt][o][tid] = mskB[cur][j][tid] ^ (1 << t);
                ++j;
            }
        }
        nb = nk;
        cur = nxt;
    }

    float e[KNN];
    float Z = 0.f;
#pragma unroll
    for (int i = 0; i < KNN; ++i) {
        e[i] = expf(-penB[cur][i][tid]);
        Z += e[i];
    }
    const float inv = 1.0f / Z;
#pragma unroll
    for (int i = 0; i < KNN; ++i) {
        sc_out[(size_t)r * KNN + i]  = e[i] * inv;
        idx_out[(size_t)r * KNN + i] = code ^ mskB[cur][i][tid];
    }
}

// ---------------------------------------------------------------------------
// Gather + embedding-bag: y[n,:] = sum_k score[n,k] * values[idx[n,k],:]
// One block (128 threads) per token; unroll 8 keeps ~8 float4 loads in
// flight per lane. HBM-bound: ~512 MB of random 2KB-row reads.
// Epilogue now emits y directly as 2 bf16 split planes (bit-identical to
// the old fp32-write + in-GEMM3 split), removing the fp32 y round-trip.
// ---------------------------------------------------------------------------
__global__ __launch_bounds__(128) void gather_kernel(
    const float* __restrict__ sc, const int* __restrict__ idx,
    const float* __restrict__ values, u16* __restrict__ ys)
{
    __shared__ float s_s[MEM_HEADS * KNN];
    __shared__ int   s_i[MEM_HEADS * KNN];
    const int n = blockIdx.x;
    const int t = threadIdx.x;          // 0..127
    s_s[t] = sc[(size_t)n * 128 + t];
    s_i[t] = idx[(size_t)n * 128 + t];
    __syncthreads();

    float4 acc = {0.f, 0.f, 0.f, 0.f};
#pragma unroll 8
    for (int k = 0; k < 128; ++k) {
        const float4 v = *(const float4*)(values + (size_t)s_i[k] * VALUE_DIM + t * 4);
        const float w = s_s[k];
        acc.x += w * v.x; acc.y += w * v.y;
        acc.z += w * v.z; acc.w += w * v.w;
    }

    float c[4] = {acc.x, acc.y, acc.z, acc.w};
    u16x4 h0, h1;
#pragma unroll
    for (int cc = 0; cc < 4; ++cc) {
        const u16 a = f2bf(c[cc]);
        h0[cc] = a;
        const float rres = c[cc] - bf2f(a);
        h1[cc] = f2bf(rres);
    }
    const size_t off = (size_t)n * VALUE_DIM + t * 4;
    *(u16x4*)(ys + off) = h0;
    *(u16x4*)(ys + (size_t)NTOK * VALUE_DIM + off) = h1;
}

// ---------------------------------------------------------------------------
extern "C" void kernel_launch(void* const* d_in, const int* in_sizes, int n_in,
                              void* d_out, int out_size, void* d_ws, size_t ws_size,
                              hipStream_t stream)
{
    (void)in_sizes; (void)n_in; (void)out_size; (void)ws_size;
    const float* x      = (const float*)d_in[0];
    const float* keys   = (const float*)d_in[1];
    const float* qd_w   = (const float*)d_in[2];
    const float* qd_b   = (const float*)d_in[3];
    const float* qu_w   = (const float*)d_in[4];
    const float* values = (const float*)d_in[5];
    const float* vp_w   = (const float*)d_in[6];
    float* out = (float*)d_out;

    char* w = (char*)d_ws;
    u16* xs  = (u16*)w;  w += (size_t)NTOK * D_MODEL * 2 * 3;      // 12 MB
    u16* qds = (u16*)w;  w += (size_t)Q_RANK * D_MODEL * 2 * 3;    // 3 MB
    u16* qus = (u16*)w;  w += (size_t)QDIM * Q_RANK * 2 * 3;       // 3.4 MB
    u16* vps = (u16*)w;  w += (size_t)D_MODEL * VALUE_DIM * 2 * 2; // 2 MB
    u16* qms = (u16*)w;  w += (size_t)NTOK * Q_RANK * 2 * 3;       // 6 MB
    u16* ys  = (u16*)w;  w += (size_t)NTOK * VALUE_DIM * 2 * 2;    // 4 MB
    float* q   = (float*)w; w += (size_t)NTOK * QDIM * 4;          // 9.4 MB
    float* sc  = (float*)w; w += (size_t)ROWS * KNN * 4;           // 1 MB
    int*   idx = (int*)w;                                          // 1 MB

    // materialize bf16 split planes of x / qd_w / qu_w (x3) and vp_w (x2)
    split_prep<<<dim3(256, 4), 256, 0, stream>>>(
        x, qd_w, qu_w, vp_w, xs, qds, qus, vps);
    // q_mid = x @ qd_w^T + qd_b  [2048,1024]@[512,1024]^T (fp32-equiv),
    // written directly as 3 bf16 split planes
    gemm_nt_pre<3, 3><<<dim3(Q_RANK / 64, NTOK / 64), 256, 0, stream>>>(
        xs, qds, qd_b, nullptr, qms, NTOK, Q_RANK, D_MODEL);
    // q = q_mid @ qu_w^T         [2048,512]@[1152,512]^T  (fp32-equiv)
    gemm_nt_pre<3, 0><<<dim3(QDIM / 64, NTOK / 64), 256, 0, stream>>>(
        qms, qus, nullptr, q, nullptr, NTOK, QDIM, Q_RANK);
    // beam search -> softmaxed scores + indices
    trellis_kernel<<<ROWS / 64, 64, 0, stream>>>(q, keys, sc, idx);
    // weighted gather -> y as 2 bf16 split planes [2048, 512]
    gather_kernel<<<NTOK, 128, 0, stream>>>(sc, idx, values, ys);
    // out = y @ vp_w^T           [2048,512]@[1024,512]^T  (bf16x3 ok)
    gemm_nt_pre<2, 0><<<dim3(D_MODEL / 64, NTOK / 64), 256, 0, stream>>>(
        ys, vps, nullptr, out, nullptr, NTOK, D_MODEL, VALUE_DIM);
}